// Round 1
// baseline (320.305 us; speedup 1.0000x reference)
//
#include <hip/hip_runtime.h>
#include <hip/hip_bf16.h>

#define S_DIM 2048
#define D_DIM 512
#define B_DIM 8
#define SCALE 0.02209708691207961f  // 1/sqrt(2048)

typedef __hip_bfloat16 bf16;
typedef short bf16x8 __attribute__((ext_vector_type(8)));
typedef float f32x4 __attribute__((ext_vector_type(4)));

__device__ __forceinline__ unsigned short f2b(float f) {
  __hip_bfloat16 h = __float2bfloat16(f);
  return __builtin_bit_cast(unsigned short, h);
}

__device__ __forceinline__ void load_lds16(const void* g, void* l) {
  __builtin_amdgcn_global_load_lds((const __attribute__((address_space(1))) void*)g,
                                   (__attribute__((address_space(3))) void*)l, 16, 0, 0);
}

// ---------------- kernel matrix f32 -> bf16 ----------------
__global__ void convert_k(const float* __restrict__ in, bf16* __restrict__ out, int n8) {
  int i = blockIdx.x * blockDim.x + threadIdx.x;
  if (i >= n8) return;
  const float4* p = (const float4*)in;
  float4 a = p[2 * i], b = p[2 * i + 1];
  bf16x8 r;
  r[0] = f2b(a.x); r[1] = f2b(a.y); r[2] = f2b(a.z); r[3] = f2b(a.w);
  r[4] = f2b(b.x); r[5] = f2b(b.y); r[6] = f2b(b.z); r[7] = f2b(b.w);
  ((bf16x8*)out)[i] = r;
}

// ---------------- transpose (B,S,D) f32 -> (B,D,S) bf16 ----------------
__global__ void transpose_f2b(const float* __restrict__ in, bf16* __restrict__ out) {
  __shared__ float tile[32][33];
  int b = blockIdx.z;
  int c0 = blockIdx.x * 32;   // D
  int r0 = blockIdx.y * 32;   // S
  const float* ib = in + (size_t)b * S_DIM * D_DIM;
  bf16* ob = out + (size_t)b * S_DIM * D_DIM;
  int lr = threadIdx.x >> 5, lc = threadIdx.x & 31;
#pragma unroll
  for (int i = 0; i < 4; i++)
    tile[lr + i * 8][lc] = ib[(size_t)(r0 + lr + i * 8) * D_DIM + c0 + lc];
  __syncthreads();
#pragma unroll
  for (int i = 0; i < 4; i++) {
    int cc = lr + i * 8;
    ob[(size_t)(c0 + cc) * S_DIM + r0 + lc] = __float2bfloat16(tile[lc][cc]);
  }
}

// ---------------- transpose (B,S,D) bf16 -> (B,D,S) bf16 ----------------
__global__ void transpose_b2b(const bf16* __restrict__ in, bf16* __restrict__ out) {
  __shared__ bf16 tile[32][33];
  int b = blockIdx.z;
  int c0 = blockIdx.x * 32;
  int r0 = blockIdx.y * 32;
  const bf16* ib = in + (size_t)b * S_DIM * D_DIM;
  bf16* ob = out + (size_t)b * S_DIM * D_DIM;
  int lr = threadIdx.x >> 5, lc = threadIdx.x & 31;
#pragma unroll
  for (int i = 0; i < 4; i++)
    tile[lr + i * 8][lc] = ib[(size_t)(r0 + lr + i * 8) * D_DIM + c0 + lc];
  __syncthreads();
#pragma unroll
  for (int i = 0; i < 4; i++) {
    int cc = lr + i * 8;
    ob[(size_t)(c0 + cc) * S_DIM + r0 + lc] = tile[lc][cc];
  }
}

// ---------------- batched GEMM: C[s][d] = sum_t A[s][t] * Bt[d][t] ----------------
// A: (2048,2048) bf16 row-major; Bt: (512,2048) bf16 per batch; C: (2048,512) bf16.
// m97 structure: 128x128 tile, BK=32, 4 waves (2x2), global_load_lds width 16.
__global__ __launch_bounds__(256, 2) void gemm_bt(
    const bf16* __restrict__ A,
    const bf16* __restrict__ B1, const bf16* __restrict__ B2,
    bf16* __restrict__ C1, bf16* __restrict__ C2) {
  const int N = D_DIM, K = S_DIM;
  __shared__ bf16 As[128][32];
  __shared__ bf16 Bs[128][32];
  int z = blockIdx.z;
  int b = z & 7, which = z >> 3;
  const bf16* Bb = (which ? B2 : B1) + (size_t)b * D_DIM * S_DIM;
  bf16* Cb = (which ? C2 : C1) + (size_t)b * S_DIM * D_DIM;
  int m0 = blockIdx.y * 128, n0 = blockIdx.x * 128;
  int tid = threadIdx.x, wave = tid >> 6, lane = tid & 63;
  int wr = wave >> 1, wc = wave & 1;
  int srow = lane >> 2;        // 0..15 within chunk
  int skh = (lane & 3) * 8;    // halfword offset (16B)
  int lr16 = lane & 15, lk = (lane >> 4) * 8;
  f32x4 acc[4][4];
#pragma unroll
  for (int m = 0; m < 4; m++)
#pragma unroll
    for (int n = 0; n < 4; n++) acc[m][n] = (f32x4){0, 0, 0, 0};

  for (int k0 = 0; k0 < K; k0 += 32) {
#pragma unroll
    for (int c = 0; c < 2; c++) {
      int chunk = wave * 2 + c;
      int row = chunk * 16 + srow;
      load_lds16(A + (size_t)(m0 + row) * K + k0 + skh, (char*)&As[0][0] + chunk * 1024);
      load_lds16(Bb + (size_t)(n0 + row) * K + k0 + skh, (char*)&Bs[0][0] + chunk * 1024);
    }
    __syncthreads();
    bf16x8 af[4], bfr[4];
#pragma unroll
    for (int m = 0; m < 4; m++) af[m] = *(const bf16x8*)&As[wr * 64 + m * 16 + lr16][lk];
#pragma unroll
    for (int n = 0; n < 4; n++) bfr[n] = *(const bf16x8*)&Bs[wc * 64 + n * 16 + lr16][lk];
#pragma unroll
    for (int m = 0; m < 4; m++)
#pragma unroll
      for (int n = 0; n < 4; n++)
        acc[m][n] = __builtin_amdgcn_mfma_f32_16x16x32_bf16(af[m], bfr[n], acc[m][n], 0, 0, 0);
    __syncthreads();
  }
#pragma unroll
  for (int m = 0; m < 4; m++) {
    int grow0 = m0 + wr * 64 + m * 16 + (lane >> 4) * 4;
#pragma unroll
    for (int n = 0; n < 4; n++) {
      int gcol = n0 + wc * 64 + n * 16 + lr16;
#pragma unroll
      for (int r = 0; r < 4; r++)
        Cb[(size_t)(grow0 + r) * N + gcol] = __float2bfloat16(acc[m][n][r]);
    }
  }
}

// ---------------- fused causal attention ----------------
// Q=h1n (s,d), K=h2n (t,d), V=h1t (d,t) all bf16; out f32 (s,d).
// 8 waves. BM=32 (2 s-strips of 16), KVB=64. QK^T: wave w -> frag(sstrip=w&1, tfrag=w>>1).
// PV: wave w owns d-chunk [w*64, w*64+64). Paired tiles {p, 63-p} for load balance.
__global__ __launch_bounds__(512) void flash_attn(
    const bf16* __restrict__ Qg, const bf16* __restrict__ Kg,
    const bf16* __restrict__ Vg, float* __restrict__ out) {
  __shared__ float Stile[32][65];
  __shared__ bf16 Ptile[32][72];
  __shared__ float mS[32], lS[32], rS[32];
  int bx = blockIdx.x;
  int b = bx & 7, pair = bx >> 3;   // batch pinned to XCD for L2 locality
  int tid = threadIdx.x, wave = tid >> 6, lane = tid & 63;
  int sstrip = wave & 1, tfrag = wave >> 1;
  int l15 = lane & 15, lhi = lane >> 4;
  const bf16* Qb = Qg + (size_t)b * S_DIM * D_DIM;
  const bf16* Kb = Kg + (size_t)b * S_DIM * D_DIM;
  const bf16* Vb = Vg + (size_t)b * S_DIM * D_DIM;
  float* Ob = out + (size_t)b * S_DIM * D_DIM;

  for (int half = 0; half < 2; half++) {
    int stile = half ? (63 - pair) : pair;
    int s0 = stile * 32;
    int nt = (s0 + 95) >> 6;  // number of 64-wide t-tiles (t <= s0+31)
    __syncthreads();
    if (tid < 32) { mS[tid] = -3e38f; lS[tid] = 0.0f; }
    __syncthreads();

    // Q fragments for this wave's s-strip: 16 rows x 512, in registers
    bf16x8 qf[16];
    {
      const bf16* qp = Qb + (size_t)(s0 + sstrip * 16 + l15) * D_DIM + lhi * 8;
#pragma unroll
      for (int c = 0; c < 16; c++) qf[c] = *(const bf16x8*)(qp + c * 32);
    }
    f32x4 oacc[2][4];
#pragma unroll
    for (int s = 0; s < 2; s++)
#pragma unroll
      for (int d = 0; d < 4; d++) oacc[s][d] = (f32x4){0, 0, 0, 0};

    for (int ti = 0; ti < nt; ti++) {
      int t0 = ti * 64;
      // 1) QK^T: one 16x16 frag per wave, K=512
      f32x4 sc = (f32x4){0, 0, 0, 0};
      {
        const bf16* kp = Kb + (size_t)(t0 + tfrag * 16 + l15) * D_DIM + lhi * 8;
#pragma unroll
        for (int c = 0; c < 16; c++) {
          bf16x8 kf = *(const bf16x8*)(kp + c * 32);
          sc = __builtin_amdgcn_mfma_f32_16x16x32_bf16(qf[c], kf, sc, 0, 0, 0);
        }
      }
      // 2) scale + causal mask -> Stile
      {
        int tg = t0 + tfrag * 16 + l15;
#pragma unroll
        for (int r = 0; r < 4; r++) {
          int row = lhi * 4 + r;
          int sg = s0 + sstrip * 16 + row;
          float v = sc[r] * SCALE;
          if (tg > sg) v = -3e38f;
          Stile[sstrip * 16 + row][tfrag * 16 + l15] = v;
        }
      }
      __syncthreads();
      // 3) online softmax: wave handles rows [wave*4, wave*4+4), 16 lanes/row
      {
        int row = wave * 4 + lhi;
        float v0 = Stile[row][l15];
        float v1 = Stile[row][l15 + 16];
        float v2 = Stile[row][l15 + 32];
        float v3 = Stile[row][l15 + 48];
        float mx = fmaxf(fmaxf(v0, v1), fmaxf(v2, v3));
#pragma unroll
        for (int off = 1; off < 16; off <<= 1) mx = fmaxf(mx, __shfl_xor(mx, off));
        float mold = mS[row];
        float mnew = fmaxf(mold, mx);
        float p0 = __expf(v0 - mnew), p1 = __expf(v1 - mnew);
        float p2 = __expf(v2 - mnew), p3 = __expf(v3 - mnew);
        float ls = p0 + p1 + p2 + p3;
#pragma unroll
        for (int off = 1; off < 16; off <<= 1) ls += __shfl_xor(ls, off);
        float rsc = __expf(mold - mnew);
        if (l15 == 0) { mS[row] = mnew; lS[row] = lS[row] * rsc + ls; rS[row] = rsc; }
        Ptile[row][l15] = __float2bfloat16(p0);
        Ptile[row][l15 + 16] = __float2bfloat16(p1);
        Ptile[row][l15 + 32] = __float2bfloat16(p2);
        Ptile[row][l15 + 48] = __float2bfloat16(p3);
      }
      __syncthreads();
      // 4) O rescale + PV (wave's 64-wide d-chunk)
      {
        float rs[2][4];
#pragma unroll
        for (int ss = 0; ss < 2; ss++)
#pragma unroll
          for (int r = 0; r < 4; r++) rs[ss][r] = rS[ss * 16 + lhi * 4 + r];
#pragma unroll
        for (int ss = 0; ss < 2; ss++)
#pragma unroll
          for (int d = 0; d < 4; d++)
#pragma unroll
            for (int r = 0; r < 4; r++) oacc[ss][d][r] *= rs[ss][r];
#pragma unroll
        for (int ks = 0; ks < 2; ks++) {
          bf16x8 vf[4];
          const bf16* vp = Vb + (size_t)(wave * 64 + l15) * S_DIM + t0 + ks * 32 + lhi * 8;
#pragma unroll
          for (int d = 0; d < 4; d++) vf[d] = *(const bf16x8*)(vp + (size_t)d * 16 * S_DIM);
#pragma unroll
          for (int ss = 0; ss < 2; ss++) {
            bf16x8 pf = *(const bf16x8*)&Ptile[ss * 16 + l15][ks * 32 + lhi * 8];
#pragma unroll
            for (int d = 0; d < 4; d++)
              oacc[ss][d] = __builtin_amdgcn_mfma_f32_16x16x32_bf16(pf, vf[d], oacc[ss][d], 0, 0, 0);
          }
        }
      }
    }
    // finalize: O /= l
#pragma unroll
    for (int ss = 0; ss < 2; ss++) {
#pragma unroll
      for (int r = 0; r < 4; r++) {
        int row = s0 + ss * 16 + lhi * 4 + r;
        float inv = 1.0f / lS[ss * 16 + lhi * 4 + r];
#pragma unroll
        for (int d = 0; d < 4; d++)
          Ob[(size_t)row * D_DIM + wave * 64 + d * 16 + l15] = oacc[ss][d][r] * inv;
      }
    }
  }
}

extern "C" void kernel_launch(void* const* d_in, const int* in_sizes, int n_in,
                              void* d_out, int out_size, void* d_ws, size_t ws_size,
                              hipStream_t stream) {
  const float* x1 = (const float*)d_in[0];
  const float* x2 = (const float*)d_in[1];
  const float* km = (const float*)d_in[2];
  float* out = (float*)d_out;
  char* ws = (char*)d_ws;
  // ws layout (bytes): Kbf 8MiB | x1t 16MiB | x2t 16MiB | h1n 16MiB | h2n 16MiB | h1t 16MiB = 88MiB
  bf16* Kbf = (bf16*)(ws);
  bf16* x1t = (bf16*)(ws + (8u << 20));
  bf16* x2t = (bf16*)(ws + (24u << 20));
  bf16* h1n = (bf16*)(ws + (40u << 20));
  bf16* h2n = (bf16*)(ws + (56u << 20));
  bf16* h1t = (bf16*)(ws + (72u << 20));

  convert_k<<<2048, 256, 0, stream>>>(km, Kbf, (S_DIM * S_DIM) / 8);
  transpose_f2b<<<dim3(16, 64, 8), 256, 0, stream>>>(x1, x1t);
  transpose_f2b<<<dim3(16, 64, 8), 256, 0, stream>>>(x2, x2t);
  gemm_bt<<<dim3(4, 16, 16), 256, 0, stream>>>(Kbf, x1t, x2t, h1n, h2n);
  transpose_b2b<<<dim3(16, 64, 8), 256, 0, stream>>>(h1n, h1t);
  flash_attn<<<256, 512, 0, stream>>>(h1n, h2n, h1t, out);
}

// Round 2
// 197.169 us; speedup vs baseline: 1.6245x; 1.6245x over previous
//
#include <hip/hip_runtime.h>
#include <hip/hip_bf16.h>

#define S_DIM 2048
#define D_DIM 512
#define B_DIM 8
#define SCALE 0.02209708691207961f  // 1/sqrt(2048)

typedef __hip_bfloat16 bf16;
typedef short bf16x8 __attribute__((ext_vector_type(8)));
typedef float f32x4 __attribute__((ext_vector_type(4)));

__device__ __forceinline__ unsigned short f2b(float f) {
  __hip_bfloat16 h = __float2bfloat16(f);
  return __builtin_bit_cast(unsigned short, h);
}

__device__ __forceinline__ void load_lds16(const void* g, void* l) {
  __builtin_amdgcn_global_load_lds((const __attribute__((address_space(1))) void*)g,
                                   (__attribute__((address_space(3))) void*)l, 16, 0, 0);
}

// ---------------- kernel matrix f32 -> bf16 ----------------
__global__ void convert_k(const float* __restrict__ in, bf16* __restrict__ out, int n8) {
  int i = blockIdx.x * blockDim.x + threadIdx.x;
  if (i >= n8) return;
  const float4* p = (const float4*)in;
  float4 a = p[2 * i], b = p[2 * i + 1];
  bf16x8 r;
  r[0] = f2b(a.x); r[1] = f2b(a.y); r[2] = f2b(a.z); r[3] = f2b(a.w);
  r[4] = f2b(b.x); r[5] = f2b(b.y); r[6] = f2b(b.z); r[7] = f2b(b.w);
  ((bf16x8*)out)[i] = r;
}

// ---------------- transpose (B,S,D) f32 -> (B,D,S) bf16 ----------------
__global__ void transpose_f2b(const float* __restrict__ in, bf16* __restrict__ out) {
  __shared__ float tile[32][33];
  int b = blockIdx.z;
  int c0 = blockIdx.x * 32;   // D
  int r0 = blockIdx.y * 32;   // S
  const float* ib = in + (size_t)b * S_DIM * D_DIM;
  bf16* ob = out + (size_t)b * S_DIM * D_DIM;
  int lr = threadIdx.x >> 5, lc = threadIdx.x & 31;
#pragma unroll
  for (int i = 0; i < 4; i++)
    tile[lr + i * 8][lc] = ib[(size_t)(r0 + lr + i * 8) * D_DIM + c0 + lc];
  __syncthreads();
#pragma unroll
  for (int i = 0; i < 4; i++) {
    int cc = lr + i * 8;
    ob[(size_t)(c0 + cc) * S_DIM + r0 + lc] = __float2bfloat16(tile[lc][cc]);
  }
}

// ---------------- transpose (B,S,D) bf16 -> (B,D,S) bf16 ----------------
__global__ void transpose_b2b(const bf16* __restrict__ in, bf16* __restrict__ out) {
  __shared__ bf16 tile[32][33];
  int b = blockIdx.z;
  int c0 = blockIdx.x * 32;
  int r0 = blockIdx.y * 32;
  const bf16* ib = in + (size_t)b * S_DIM * D_DIM;
  bf16* ob = out + (size_t)b * S_DIM * D_DIM;
  int lr = threadIdx.x >> 5, lc = threadIdx.x & 31;
#pragma unroll
  for (int i = 0; i < 4; i++)
    tile[lr + i * 8][lc] = ib[(size_t)(r0 + lr + i * 8) * D_DIM + c0 + lc];
  __syncthreads();
#pragma unroll
  for (int i = 0; i < 4; i++) {
    int cc = lr + i * 8;
    ob[(size_t)(c0 + cc) * S_DIM + r0 + lc] = tile[lc][cc];
  }
}

// ---------------- batched GEMM: C[s][d] = sum_t A[s][t] * Bt[d][t] ----------------
// A: (2048,2048) bf16 row-major; Bt: (512,2048) bf16 per batch; C: (2048,512) bf16.
__global__ __launch_bounds__(256, 2) void gemm_bt(
    const bf16* __restrict__ A,
    const bf16* __restrict__ B1, const bf16* __restrict__ B2,
    bf16* __restrict__ C1, bf16* __restrict__ C2) {
  const int N = D_DIM, K = S_DIM;
  __shared__ bf16 As[128][32];
  __shared__ bf16 Bs[128][32];
  int z = blockIdx.z;
  int b = z & 7, which = z >> 3;
  const bf16* Bb = (which ? B2 : B1) + (size_t)b * D_DIM * S_DIM;
  bf16* Cb = (which ? C2 : C1) + (size_t)b * S_DIM * D_DIM;
  int m0 = blockIdx.y * 128, n0 = blockIdx.x * 128;
  int tid = threadIdx.x, wave = tid >> 6, lane = tid & 63;
  int wr = wave >> 1, wc = wave & 1;
  int srow = lane >> 2;
  int skh = (lane & 3) * 8;
  int lr16 = lane & 15, lk = (lane >> 4) * 8;
  f32x4 acc[4][4];
#pragma unroll
  for (int m = 0; m < 4; m++)
#pragma unroll
    for (int n = 0; n < 4; n++) acc[m][n] = (f32x4){0, 0, 0, 0};

  for (int k0 = 0; k0 < K; k0 += 32) {
#pragma unroll
    for (int c = 0; c < 2; c++) {
      int chunk = wave * 2 + c;
      int row = chunk * 16 + srow;
      load_lds16(A + (size_t)(m0 + row) * K + k0 + skh, (char*)&As[0][0] + chunk * 1024);
      load_lds16(Bb + (size_t)(n0 + row) * K + k0 + skh, (char*)&Bs[0][0] + chunk * 1024);
    }
    __syncthreads();
    bf16x8 af[4], bfr[4];
#pragma unroll
    for (int m = 0; m < 4; m++) af[m] = *(const bf16x8*)&As[wr * 64 + m * 16 + lr16][lk];
#pragma unroll
    for (int n = 0; n < 4; n++) bfr[n] = *(const bf16x8*)&Bs[wc * 64 + n * 16 + lr16][lk];
#pragma unroll
    for (int m = 0; m < 4; m++)
#pragma unroll
      for (int n = 0; n < 4; n++)
        acc[m][n] = __builtin_amdgcn_mfma_f32_16x16x32_bf16(af[m], bfr[n], acc[m][n], 0, 0, 0);
    __syncthreads();
  }
#pragma unroll
  for (int m = 0; m < 4; m++) {
    int grow0 = m0 + wr * 64 + m * 16 + (lane >> 4) * 4;
#pragma unroll
    for (int n = 0; n < 4; n++) {
      int gcol = n0 + wc * 64 + n * 16 + lr16;
#pragma unroll
      for (int r = 0; r < 4; r++)
        Cb[(size_t)(grow0 + r) * N + gcol] = __float2bfloat16(acc[m][n][r]);
    }
  }
}

// ---------------- score GEMM + exp epilogue ----------------
// E[s][t] = exp(SCALE * sum_d h1[s][d]*h2[t][d]) for t<=s else 0 (bf16),
// rowsum[s] += partial sums. Lower-triangular 128x128 tiles only.
// grid: 136 tri-tiles * 8 batches; pid&7 = batch (XCD-pinned).
__global__ __launch_bounds__(256, 2) void gemm_score(
    const bf16* __restrict__ H1, const bf16* __restrict__ H2,
    bf16* __restrict__ E, float* __restrict__ rowsum) {
  const int K = D_DIM;
  __shared__ bf16 As[128][32];
  __shared__ bf16 Bs[128][32];
  int pid = blockIdx.x;
  int b = pid & 7, tri = pid >> 3;
  int mt = (int)((sqrtf(8.0f * (float)tri + 1.0f) - 1.0f) * 0.5f);
  while ((mt + 1) * (mt + 2) / 2 <= tri) mt++;
  while (mt * (mt + 1) / 2 > tri) mt--;
  int nt = tri - mt * (mt + 1) / 2;
  const bf16* Ab = H1 + (size_t)b * S_DIM * D_DIM;
  const bf16* Bb = H2 + (size_t)b * S_DIM * D_DIM;
  bf16* Eb = E + (size_t)b * S_DIM * S_DIM;
  float* rs = rowsum + b * S_DIM;
  int m0 = mt * 128, n0 = nt * 128;
  int tid = threadIdx.x, wave = tid >> 6, lane = tid & 63;
  int wr = wave >> 1, wc = wave & 1;
  int srow = lane >> 2;
  int skh = (lane & 3) * 8;
  int l15 = lane & 15, lhi = lane >> 4;
  int lk = lhi * 8;
  f32x4 acc[4][4];
#pragma unroll
  for (int m = 0; m < 4; m++)
#pragma unroll
    for (int n = 0; n < 4; n++) acc[m][n] = (f32x4){0, 0, 0, 0};

  for (int k0 = 0; k0 < K; k0 += 32) {
#pragma unroll
    for (int c = 0; c < 2; c++) {
      int chunk = wave * 2 + c;
      int row = chunk * 16 + srow;
      load_lds16(Ab + (size_t)(m0 + row) * K + k0 + skh, (char*)&As[0][0] + chunk * 1024);
      load_lds16(Bb + (size_t)(n0 + row) * K + k0 + skh, (char*)&Bs[0][0] + chunk * 1024);
    }
    __syncthreads();
    bf16x8 af[4], bfr[4];
#pragma unroll
    for (int m = 0; m < 4; m++) af[m] = *(const bf16x8*)&As[wr * 64 + m * 16 + l15][lk];
#pragma unroll
    for (int n = 0; n < 4; n++) bfr[n] = *(const bf16x8*)&Bs[wc * 64 + n * 16 + l15][lk];
#pragma unroll
    for (int m = 0; m < 4; m++)
#pragma unroll
      for (int n = 0; n < 4; n++)
        acc[m][n] = __builtin_amdgcn_mfma_f32_16x16x32_bf16(af[m], bfr[n], acc[m][n], 0, 0, 0);
    __syncthreads();
  }
  // epilogue: exp + causal mask + bf16 store + partial rowsum
  float rp[4][4];
#pragma unroll
  for (int m = 0; m < 4; m++)
#pragma unroll
    for (int r = 0; r < 4; r++) rp[m][r] = 0.0f;
#pragma unroll
  for (int m = 0; m < 4; m++) {
#pragma unroll
    for (int n = 0; n < 4; n++) {
      int tg = n0 + wc * 64 + n * 16 + l15;
#pragma unroll
      for (int r = 0; r < 4; r++) {
        int sg = m0 + wr * 64 + m * 16 + lhi * 4 + r;
        float v = 0.0f;
        if (tg <= sg) v = __expf(acc[m][n][r] * SCALE);
        bf16 bv = __float2bfloat16(v);
        Eb[(size_t)sg * S_DIM + tg] = bv;
        rp[m][r] += __bfloat162float(bv);
      }
    }
  }
#pragma unroll
  for (int m = 0; m < 4; m++) {
#pragma unroll
    for (int r = 0; r < 4; r++) {
      float v = rp[m][r];
#pragma unroll
      for (int off = 1; off < 16; off <<= 1) v += __shfl_xor(v, off);
      if (l15 == 0) {
        int sg = m0 + wr * 64 + m * 16 + lhi * 4 + r;
        atomicAdd(rs + sg, v);
      }
    }
  }
}

// ---------------- PV GEMM: out[s][d] = (1/rowsum[s]) * sum_t E[s][t]*h1t[d][t] ----------------
// Causal: K-loop only to (mt+1)*128. m-tile scramble balances K-depth across CUs.
// grid: 512 = 8 batches (pid&7, XCD-pinned) * 4 n-tiles * 16 m-tiles.
__global__ __launch_bounds__(256, 2) void gemm_pv(
    const bf16* __restrict__ E, const bf16* __restrict__ H1T,
    const float* __restrict__ rowsum, float* __restrict__ out) {
  __shared__ bf16 As[128][32];
  __shared__ bf16 Bs[128][32];
  int pid = blockIdx.x;
  int b = pid & 7;
  int r_ = pid >> 3;            // 0..63
  int nt = r_ & 3;
  int mb = r_ >> 2;             // 0..15
  int mt = (mb < 8) ? 2 * mb : 31 - 2 * mb;
  int m0 = mt * 128, n0 = nt * 128;
  int KMAX = (mt + 1) * 128;
  const bf16* Ab = E + (size_t)b * S_DIM * S_DIM;     // stride S_DIM
  const bf16* Bb = H1T + (size_t)b * D_DIM * S_DIM;   // [512][2048], stride S_DIM
  const float* rs = rowsum + b * S_DIM;
  float* Cb = out + (size_t)b * S_DIM * D_DIM;
  int tid = threadIdx.x, wave = tid >> 6, lane = tid & 63;
  int wr = wave >> 1, wc = wave & 1;
  int srow = lane >> 2;
  int skh = (lane & 3) * 8;
  int l15 = lane & 15, lhi = lane >> 4;
  int lk = lhi * 8;
  f32x4 acc[4][4];
#pragma unroll
  for (int m = 0; m < 4; m++)
#pragma unroll
    for (int n = 0; n < 4; n++) acc[m][n] = (f32x4){0, 0, 0, 0};

  for (int k0 = 0; k0 < KMAX; k0 += 32) {
#pragma unroll
    for (int c = 0; c < 2; c++) {
      int chunk = wave * 2 + c;
      int row = chunk * 16 + srow;
      load_lds16(Ab + (size_t)(m0 + row) * S_DIM + k0 + skh, (char*)&As[0][0] + chunk * 1024);
      load_lds16(Bb + (size_t)(n0 + row) * S_DIM + k0 + skh, (char*)&Bs[0][0] + chunk * 1024);
    }
    __syncthreads();
    bf16x8 af[4], bfr[4];
#pragma unroll
    for (int m = 0; m < 4; m++) af[m] = *(const bf16x8*)&As[wr * 64 + m * 16 + l15][lk];
#pragma unroll
    for (int n = 0; n < 4; n++) bfr[n] = *(const bf16x8*)&Bs[wc * 64 + n * 16 + l15][lk];
#pragma unroll
    for (int m = 0; m < 4; m++)
#pragma unroll
      for (int n = 0; n < 4; n++)
        acc[m][n] = __builtin_amdgcn_mfma_f32_16x16x32_bf16(af[m], bfr[n], acc[m][n], 0, 0, 0);
    __syncthreads();
  }
#pragma unroll
  for (int m = 0; m < 4; m++) {
#pragma unroll
    for (int r = 0; r < 4; r++) {
      int sg = m0 + wr * 64 + m * 16 + lhi * 4 + r;
      float inv = 1.0f / rs[sg];
#pragma unroll
      for (int n = 0; n < 4; n++) {
        int gcol = n0 + wc * 64 + n * 16 + l15;
        Cb[(size_t)sg * D_DIM + gcol] = acc[m][n][r] * inv;
      }
    }
  }
}

extern "C" void kernel_launch(void* const* d_in, const int* in_sizes, int n_in,
                              void* d_out, int out_size, void* d_ws, size_t ws_size,
                              hipStream_t stream) {
  const float* x1 = (const float*)d_in[0];
  const float* x2 = (const float*)d_in[1];
  const float* km = (const float*)d_in[2];
  float* out = (float*)d_out;
  char* ws = (char*)d_ws;
  // ws layout (bytes):
  //   [0,64M):   E (8 x 2048 x 2048 bf16)  -- written after phase-1 temporaries die
  //   [0,8M):    Kbf   (phase 1 only, overlaps E)
  //   [8,24M):   x1t   (phase 1 only, overlaps E)
  //   [24,40M):  x2t   (phase 1 only, overlaps E)
  //   [64,80M):  h1n   [80,96M): h2n   [96,112M): h1t
  //   [112M, +64K): rowsum (8 x 2048 f32)
  bf16* E    = (bf16*)(ws);
  bf16* Kbf  = (bf16*)(ws);
  bf16* x1t  = (bf16*)(ws + (8ull << 20));
  bf16* x2t  = (bf16*)(ws + (24ull << 20));
  bf16* h1n  = (bf16*)(ws + (64ull << 20));
  bf16* h2n  = (bf16*)(ws + (80ull << 20));
  bf16* h1t  = (bf16*)(ws + (96ull << 20));
  float* rowsum = (float*)(ws + (112ull << 20));

  convert_k<<<2048, 256, 0, stream>>>(km, Kbf, (S_DIM * S_DIM) / 8);
  transpose_f2b<<<dim3(16, 64, 8), 256, 0, stream>>>(x1, x1t);
  transpose_f2b<<<dim3(16, 64, 8), 256, 0, stream>>>(x2, x2t);
  gemm_bt<<<dim3(4, 16, 16), 256, 0, stream>>>(Kbf, x1t, x2t, h1n, h2n);
  transpose_b2b<<<dim3(16, 64, 8), 256, 0, stream>>>(h1n, h1t);
  hipMemsetAsync(rowsum, 0, B_DIM * S_DIM * sizeof(float), stream);
  gemm_score<<<136 * 8, 256, 0, stream>>>(h1n, h2n, E, rowsum);
  gemm_pv<<<512, 256, 0, stream>>>(E, h1t, rowsum, out);
}

// Round 3
// 190.452 us; speedup vs baseline: 1.6818x; 1.0353x over previous
//
#include <hip/hip_runtime.h>
#include <hip/hip_bf16.h>

#define S_DIM 2048
#define D_DIM 512
#define B_DIM 8
#define SCALE 0.02209708691207961f  // 1/sqrt(2048)

typedef __hip_bfloat16 bf16;
typedef short bf16x8 __attribute__((ext_vector_type(8)));
typedef float f32x4 __attribute__((ext_vector_type(4)));

__device__ __forceinline__ unsigned short f2b(float f) {
  __hip_bfloat16 h = __float2bfloat16(f);
  return __builtin_bit_cast(unsigned short, h);
}

__device__ __forceinline__ void load_lds16(const void* g, void* l) {
  __builtin_amdgcn_global_load_lds((const __attribute__((address_space(1))) void*)g,
                                   (__attribute__((address_space(3))) void*)l, 16, 0, 0);
}

// ---------------- kernel matrix f32 -> bf16 ----------------
__global__ void convert_k(const float* __restrict__ in, bf16* __restrict__ out, int n8) {
  int i = blockIdx.x * blockDim.x + threadIdx.x;
  if (i >= n8) return;
  const float4* p = (const float4*)in;
  float4 a = p[2 * i], b = p[2 * i + 1];
  bf16x8 r;
  r[0] = f2b(a.x); r[1] = f2b(a.y); r[2] = f2b(a.z); r[3] = f2b(a.w);
  r[4] = f2b(b.x); r[5] = f2b(b.y); r[6] = f2b(b.z); r[7] = f2b(b.w);
  ((bf16x8*)out)[i] = r;
}

// ---------------- transpose (B,S,D) f32 -> (B,D,S) bf16 ----------------
__global__ void transpose_f2b(const float* __restrict__ in, bf16* __restrict__ out) {
  __shared__ float tile[32][33];
  int b = blockIdx.z;
  int c0 = blockIdx.x * 32;   // D
  int r0 = blockIdx.y * 32;   // S
  const float* ib = in + (size_t)b * S_DIM * D_DIM;
  bf16* ob = out + (size_t)b * S_DIM * D_DIM;
  int lr = threadIdx.x >> 5, lc = threadIdx.x & 31;
#pragma unroll
  for (int i = 0; i < 4; i++)
    tile[lr + i * 8][lc] = ib[(size_t)(r0 + lr + i * 8) * D_DIM + c0 + lc];
  __syncthreads();
#pragma unroll
  for (int i = 0; i < 4; i++) {
    int cc = lr + i * 8;
    ob[(size_t)(c0 + cc) * S_DIM + r0 + lc] = __float2bfloat16(tile[lc][cc]);
  }
}

// ---------------- transpose (B,S,D) bf16 -> (B,D,S) bf16 ----------------
__global__ void transpose_b2b(const bf16* __restrict__ in, bf16* __restrict__ out) {
  __shared__ bf16 tile[32][33];
  int b = blockIdx.z;
  int c0 = blockIdx.x * 32;
  int r0 = blockIdx.y * 32;
  const bf16* ib = in + (size_t)b * S_DIM * D_DIM;
  bf16* ob = out + (size_t)b * S_DIM * D_DIM;
  int lr = threadIdx.x >> 5, lc = threadIdx.x & 31;
#pragma unroll
  for (int i = 0; i < 4; i++)
    tile[lr + i * 8][lc] = ib[(size_t)(r0 + lr + i * 8) * D_DIM + c0 + lc];
  __syncthreads();
#pragma unroll
  for (int i = 0; i < 4; i++) {
    int cc = lr + i * 8;
    ob[(size_t)(c0 + cc) * S_DIM + r0 + lc] = tile[lc][cc];
  }
}

// ---------------- h-GEMM, pipelined: H[item][s][d] = sum_t A[s][t] * X[item][d][t] ----
// A: (2048,2048) bf16; X: 16 contiguous items of (512,2048) bf16 (x^T);
// H: 16 contiguous items of (2048,512) bf16.
// BM=256 BN=128 BK=64, 8 waves (4m x 2n), triple-buffered LDS (144 KiB),
// counted vmcnt(6), 1 barrier/K-step, XOR-swizzled LDS via pre-swizzled source.
__global__ __launch_bounds__(512, 2) void gemm_h(
    const bf16* __restrict__ A, const bf16* __restrict__ X, bf16* __restrict__ H) {
  extern __shared__ char smem[];   // [0,96K): A bufs 3x32K; [96K,144K): B bufs 3x16K
  const int pid = blockIdx.x;
  const int item = pid & 15;            // pid&7 = XCD: item's panels stay in one L2
  const int tt = pid >> 4;              // 0..31
  const int mt = tt >> 2, ntl = tt & 3;
  const int m0 = mt * 256, n0 = ntl * 128;
  const bf16* Xi = X + (size_t)item * (D_DIM * S_DIM);
  bf16* Hi = H + (size_t)item * (S_DIM * D_DIM);

  const int tid = threadIdx.x;
  const int w = tid >> 6, L = tid & 63;
  const int l15 = L & 15, lhi = L >> 4;
  const int wr = w >> 1, wc = w & 1;
  const int lr8 = L >> 3;                  // 0..7
  const int sslot = ((L & 7) ^ lr8) * 8;   // pre-swizzled source slot (elements)

  // global source pointers (swizzled); k advances by t2*64 elements
  const bf16* paA[4];
  const bf16* paB[2];
#pragma unroll
  for (int ld = 0; ld < 4; ld++)
    paA[ld] = A + (size_t)(m0 + 32 * w + 8 * ld + lr8) * 2048 + sslot;
#pragma unroll
  for (int ld = 0; ld < 2; ld++)
    paB[ld] = Xi + (size_t)(n0 + 16 * w + 8 * ld + lr8) * 2048 + sslot;

  char* rA0 = smem;
  char* rA1 = smem + 32768;
  char* rA2 = smem + 65536;
  char* rB0 = smem + 98304;
  char* rB1 = smem + 98304 + 16384;
  char* rB2 = smem + 98304 + 32768;

  auto stage = [&](int t2, char* dA, char* dB) {
#pragma unroll
    for (int ld = 0; ld < 4; ld++)
      load_lds16(paA[ld] + t2 * 64, dA + ((w * 4 + ld) << 10));
#pragma unroll
    for (int ld = 0; ld < 2; ld++)
      load_lds16(paB[ld] + t2 * 64, dB + ((w * 2 + ld) << 10));
  };

  // swizzled ds_read byte offsets: row*128 + (slot ^ (row&7))*16
  int offA[2][4], offB[2][4];
#pragma unroll
  for (int kk = 0; kk < 2; kk++) {
#pragma unroll
    for (int m = 0; m < 4; m++)
      offA[kk][m] = (wr * 64 + m * 16 + l15) * 128 + ((((kk << 2) + lhi) ^ (L & 7)) << 4);
#pragma unroll
    for (int n = 0; n < 4; n++)
      offB[kk][n] = (wc * 64 + n * 16 + l15) * 128 + ((((kk << 2) + lhi) ^ (L & 7)) << 4);
  }

  f32x4 acc[4][4];
#pragma unroll
  for (int m = 0; m < 4; m++)
#pragma unroll
    for (int n = 0; n < 4; n++) acc[m][n] = (f32x4){0, 0, 0, 0};

  stage(0, rA0, rB0);
  stage(1, rA1, rB1);

#pragma unroll 1
  for (int t = 0; t < 32; ++t) {
    // tile t complete (own wave); tile t+1's 6 loads stay in flight across the barrier
    if (t < 31) asm volatile("s_waitcnt vmcnt(6)" ::: "memory");
    else        asm volatile("s_waitcnt vmcnt(0)" ::: "memory");
    __builtin_amdgcn_s_barrier();      // all waves' tile-t parts landed
    asm volatile("" ::: "memory");
    // stage t+2 into the buffer whose content (tile t-1) was fully read before
    // any wave could pass the barrier above (its consuming MFMAs already issued).
    if (t < 30) stage(t + 2, rA2, rB2);

    bf16x8 af[2][4], bfr[2][4];
#pragma unroll
    for (int kk = 0; kk < 2; kk++) {
#pragma unroll
      for (int m = 0; m < 4; m++) af[kk][m] = *(const bf16x8*)(rA0 + offA[kk][m]);
#pragma unroll
      for (int n = 0; n < 4; n++) bfr[kk][n] = *(const bf16x8*)(rB0 + offB[kk][n]);
    }
    __builtin_amdgcn_s_setprio(1);
#pragma unroll
    for (int kk = 0; kk < 2; kk++)
#pragma unroll
      for (int m = 0; m < 4; m++)
#pragma unroll
        for (int n = 0; n < 4; n++)
          acc[m][n] = __builtin_amdgcn_mfma_f32_16x16x32_bf16(af[kk][m], bfr[kk][n], acc[m][n], 0, 0, 0);
    __builtin_amdgcn_s_setprio(0);

    char* tA = rA0; rA0 = rA1; rA1 = rA2; rA2 = tA;
    char* tB = rB0; rB0 = rB1; rB1 = rB2; rB2 = tB;
  }

#pragma unroll
  for (int m = 0; m < 4; m++) {
#pragma unroll
    for (int n = 0; n < 4; n++) {
      int col = n0 + wc * 64 + n * 16 + l15;
#pragma unroll
      for (int r = 0; r < 4; r++) {
        int row = m0 + wr * 64 + m * 16 + lhi * 4 + r;
        Hi[(size_t)row * D_DIM + col] = __float2bfloat16(acc[m][n][r]);
      }
    }
  }
}

// ---------------- score GEMM + exp epilogue ----------------
// E[s][t] = exp(SCALE * sum_d h1[s][d]*h2[t][d]) for t<=s else 0 (bf16),
// rowsum[s] += partial sums. Lower-triangular 128x128 tiles only.
__global__ __launch_bounds__(256, 2) void gemm_score(
    const bf16* __restrict__ H1, const bf16* __restrict__ H2,
    bf16* __restrict__ E, float* __restrict__ rowsum) {
  const int K = D_DIM;
  __shared__ bf16 As[128][32];
  __shared__ bf16 Bs[128][32];
  int pid = blockIdx.x;
  int b = pid & 7, tri = pid >> 3;
  int mt = (int)((sqrtf(8.0f * (float)tri + 1.0f) - 1.0f) * 0.5f);
  while ((mt + 1) * (mt + 2) / 2 <= tri) mt++;
  while (mt * (mt + 1) / 2 > tri) mt--;
  int nt = tri - mt * (mt + 1) / 2;
  const bf16* Ab = H1 + (size_t)b * S_DIM * D_DIM;
  const bf16* Bb = H2 + (size_t)b * S_DIM * D_DIM;
  bf16* Eb = E + (size_t)b * S_DIM * S_DIM;
  float* rs = rowsum + b * S_DIM;
  int m0 = mt * 128, n0 = nt * 128;
  int tid = threadIdx.x, wave = tid >> 6, lane = tid & 63;
  int wr = wave >> 1, wc = wave & 1;
  int srow = lane >> 2;
  int skh = (lane & 3) * 8;
  int l15 = lane & 15, lhi = lane >> 4;
  int lk = lhi * 8;
  f32x4 acc[4][4];
#pragma unroll
  for (int m = 0; m < 4; m++)
#pragma unroll
    for (int n = 0; n < 4; n++) acc[m][n] = (f32x4){0, 0, 0, 0};

  for (int k0 = 0; k0 < K; k0 += 32) {
#pragma unroll
    for (int c = 0; c < 2; c++) {
      int chunk = wave * 2 + c;
      int row = chunk * 16 + srow;
      load_lds16(Ab + (size_t)(m0 + row) * K + k0 + skh, (char*)&As[0][0] + chunk * 1024);
      load_lds16(Bb + (size_t)(n0 + row) * K + k0 + skh, (char*)&Bs[0][0] + chunk * 1024);
    }
    __syncthreads();
    bf16x8 af[4], bfr[4];
#pragma unroll
    for (int m = 0; m < 4; m++) af[m] = *(const bf16x8*)&As[wr * 64 + m * 16 + l15][lk];
#pragma unroll
    for (int n = 0; n < 4; n++) bfr[n] = *(const bf16x8*)&Bs[wc * 64 + n * 16 + l15][lk];
#pragma unroll
    for (int m = 0; m < 4; m++)
#pragma unroll
      for (int n = 0; n < 4; n++)
        acc[m][n] = __builtin_amdgcn_mfma_f32_16x16x32_bf16(af[m], bfr[n], acc[m][n], 0, 0, 0);
    __syncthreads();
  }
  float rp[4][4];
#pragma unroll
  for (int m = 0; m < 4; m++)
#pragma unroll
    for (int r = 0; r < 4; r++) rp[m][r] = 0.0f;
#pragma unroll
  for (int m = 0; m < 4; m++) {
#pragma unroll
    for (int n = 0; n < 4; n++) {
      int tg = n0 + wc * 64 + n * 16 + l15;
#pragma unroll
      for (int r = 0; r < 4; r++) {
        int sg = m0 + wr * 64 + m * 16 + lhi * 4 + r;
        float v = 0.0f;
        if (tg <= sg) v = __expf(acc[m][n][r] * SCALE);
        bf16 bv = __float2bfloat16(v);
        Eb[(size_t)sg * S_DIM + tg] = bv;
        rp[m][r] += __bfloat162float(bv);
      }
    }
  }
#pragma unroll
  for (int m = 0; m < 4; m++) {
#pragma unroll
    for (int r = 0; r < 4; r++) {
      float v = rp[m][r];
#pragma unroll
      for (int off = 1; off < 16; off <<= 1) v += __shfl_xor(v, off);
      if (l15 == 0) {
        int sg = m0 + wr * 64 + m * 16 + lhi * 4 + r;
        atomicAdd(rs + sg, v);
      }
    }
  }
}

// ---------------- PV GEMM: out[s][d] = (1/rowsum[s]) * sum_t E[s][t]*h1t[d][t] ----
__global__ __launch_bounds__(256, 2) void gemm_pv(
    const bf16* __restrict__ E, const bf16* __restrict__ H1T,
    const float* __restrict__ rowsum, float* __restrict__ out) {
  __shared__ bf16 As[128][32];
  __shared__ bf16 Bs[128][32];
  int pid = blockIdx.x;
  int b = pid & 7;
  int r_ = pid >> 3;
  int nt = r_ & 3;
  int mb = r_ >> 2;
  int mt = (mb < 8) ? 2 * mb : 31 - 2 * mb;
  int m0 = mt * 128, n0 = nt * 128;
  int KMAX = (mt + 1) * 128;
  const bf16* Ab = E + (size_t)b * S_DIM * S_DIM;
  const bf16* Bb = H1T + (size_t)b * D_DIM * S_DIM;
  const float* rs = rowsum + b * S_DIM;
  float* Cb = out + (size_t)b * S_DIM * D_DIM;
  int tid = threadIdx.x, wave = tid >> 6, lane = tid & 63;
  int wr = wave >> 1, wc = wave & 1;
  int srow = lane >> 2;
  int skh = (lane & 3) * 8;
  int l15 = lane & 15, lhi = lane >> 4;
  int lk = lhi * 8;
  f32x4 acc[4][4];
#pragma unroll
  for (int m = 0; m < 4; m++)
#pragma unroll
    for (int n = 0; n < 4; n++) acc[m][n] = (f32x4){0, 0, 0, 0};

  for (int k0 = 0; k0 < KMAX; k0 += 32) {
#pragma unroll
    for (int c = 0; c < 2; c++) {
      int chunk = wave * 2 + c;
      int row = chunk * 16 + srow;
      load_lds16(Ab + (size_t)(m0 + row) * S_DIM + k0 + skh, (char*)&As[0][0] + chunk * 1024);
      load_lds16(Bb + (size_t)(n0 + row) * S_DIM + k0 + skh, (char*)&Bs[0][0] + chunk * 1024);
    }
    __syncthreads();
    bf16x8 af[4], bfr[4];
#pragma unroll
    for (int m = 0; m < 4; m++) af[m] = *(const bf16x8*)&As[wr * 64 + m * 16 + l15][lk];
#pragma unroll
    for (int n = 0; n < 4; n++) bfr[n] = *(const bf16x8*)&Bs[wc * 64 + n * 16 + l15][lk];
#pragma unroll
    for (int m = 0; m < 4; m++)
#pragma unroll
      for (int n = 0; n < 4; n++)
        acc[m][n] = __builtin_amdgcn_mfma_f32_16x16x32_bf16(af[m], bfr[n], acc[m][n], 0, 0, 0);
    __syncthreads();
  }
#pragma unroll
  for (int m = 0; m < 4; m++) {
#pragma unroll
    for (int r = 0; r < 4; r++) {
      int sg = m0 + wr * 64 + m * 16 + lhi * 4 + r;
      float inv = 1.0f / rs[sg];
#pragma unroll
      for (int n = 0; n < 4; n++) {
        int gcol = n0 + wc * 64 + n * 16 + l15;
        Cb[(size_t)sg * D_DIM + gcol] = acc[m][n][r] * inv;
      }
    }
  }
}

extern "C" void kernel_launch(void* const* d_in, const int* in_sizes, int n_in,
                              void* d_out, int out_size, void* d_ws, size_t ws_size,
                              hipStream_t stream) {
  const float* x1 = (const float*)d_in[0];
  const float* x2 = (const float*)d_in[1];
  const float* km = (const float*)d_in[2];
  float* out = (float*)d_out;
  char* ws = (char*)d_ws;
  // ws layout (bytes):
  //   [0,64M):   E (8 x 2048 x 2048 bf16) -- overlaps the phase-1 temporaries below
  //   [0,8M):    Kbf | [8,24M): x1t | [24,40M): x2t   (dead before E is written)
  //   [64,80M):  h1n  [80,96M): h2n  [96,112M): h1t
  //   [112M,+64K): rowsum (8 x 2048 f32)
  bf16* E    = (bf16*)(ws);
  bf16* Kbf  = (bf16*)(ws);
  bf16* x1t  = (bf16*)(ws + (8ull << 20));
  bf16* h1n  = (bf16*)(ws + (64ull << 20));
  bf16* h1t  = (bf16*)(ws + (96ull << 20));
  float* rowsum = (float*)(ws + (112ull << 20));
  bf16* h2n  = (bf16*)(ws + (80ull << 20));

  convert_k<<<2048, 256, 0, stream>>>(km, Kbf, (S_DIM * S_DIM) / 8);
  transpose_f2b<<<dim3(16, 64, 8), 256, 0, stream>>>(x1, x1t);
  transpose_f2b<<<dim3(16, 64, 8), 256, 0, stream>>>(x2, (bf16*)(ws + (24ull << 20)));
  // x1t..x2t are contiguous: 16 items of (512,2048); outputs h1n..h2n contiguous.
  gemm_h<<<512, 512, 147456, stream>>>(Kbf, x1t, h1n);
  transpose_b2b<<<dim3(16, 64, 8), 256, 0, stream>>>(h1n, h1t);
  hipMemsetAsync(rowsum, 0, B_DIM * S_DIM * sizeof(float), stream);
  gemm_score<<<136 * 8, 256, 0, stream>>>(h1n, h2n, E, rowsum);
  gemm_pv<<<512, 256, 0, stream>>>(E, h1t, rowsum, out);
}